// Round 14
// baseline (92.055 us; speedup 1.0000x reference)
//
#include <hip/hip_runtime.h>

// ---------------- problem constants ----------------
#define Bb 10
#define Hh 50
#define Ww 101
#define Kk 4096
#define SLICE (Hh*Ww)   // 5050

// conv1: IC=3 OC=32 k7 s2 p3 -> [32,25,51]; pool1 k3 s2 -> [32,12,25]
// conv2: IC=32 OC=64 k5 s1 p2 -> [64,12,25]; pool2 k2 s2 -> [64,6,12]
// conv3: IC=64 OC=128 k3 s1 p1 -> [128,6,12]; pool3 k2 s2 -> [128,3,6]
// head: mean(18) -> fc128 relu -> fc5

// ============ K0: scatter + separable 3x3 max-dilate + decode -> grid ============
// 30 blocks x 1024 threads (R8 verbatim). Also zeroes cnt[0..9] for K3.
__global__ __launch_bounds__(1024) void scatter_grid_kernel(
        const int* __restrict__ x, float* __restrict__ grid, unsigned* __restrict__ cnt) {
    __shared__ int lastKp[52 * 104];   // [row+1][col+1], border -1
    __shared__ int rowm[52 * 104];     // horizontal 3-max
    int bc = blockIdx.x;
    int tid = threadIdx.x;
    if (bc < Bb && tid == 0)
        __hip_atomic_store(&cnt[bc], 0u, __ATOMIC_RELEASE, __HIP_MEMORY_SCOPE_AGENT);
    for (int i = tid; i < 52 * 104; i += 1024) lastKp[i] = -1;
    __syncthreads();
    const int2* xp = (const int2*)(x + bc * Kk * 2);   // (col,row) pairs
    for (int k = tid; k < Kk + 1; k += 1024) {
        int col, row;
        if (k == 0) { col = 50; row = 48; }            // prepended base fill
        else { int2 p = xp[k - 1]; col = p.x; row = p.y; }
        atomicMax(&lastKp[(row + 1) * 104 + (col + 1)], k);
    }
    __syncthreads();
    for (int i = tid; i < 52 * 101; i += 1024) {       // row-max pass
        int r = i / 101, c = i % 101 + 1;
        const int* lp = &lastKp[r * 104 + c];
        rowm[r * 104 + c] = max(max(lp[-1], lp[0]), lp[1]);
    }
    __syncthreads();
    float* g = grid + bc * SLICE;                      // col-max + decode
    for (int i = tid; i < SLICE; i += 1024) {
        int r = i / Ww + 1, c = i % Ww + 1;
        int M = max(max(rowm[(r - 1) * 104 + c], rowm[r * 104 + c]),
                    rowm[(r + 1) * 104 + c]);
        g[i] = (M < 0) ? 0.0f : ((lastKp[r * 104 + c] == M) ? 1.0f : 0.5f);
    }
}

// ======== K1 v3: conv1 + pool1, high-occupancy band-tiled (480 blocks x 256) ========
// block = (b, ocq in [0,8), phb in [0,6)). Covers pool rows ph = 2*phb..2*phb+1
// (conv rows 4*phb..4*phb+4, bands overlap 1 conv row -> benign redundant
// compute, exclusive p1 writes). Input tile [3][15][107] + 4-oc weights in LDS.
// R13 bug fixed: conv col base is 2*ow (stride-2), was ow.
__global__ __launch_bounds__(256) void conv1p1_kernel(
        const float* __restrict__ grid, const float* __restrict__ w1,
        const float* __restrict__ b1, float* __restrict__ p1) {
    __shared__ float tile[3 * 15 * 107];   // 19260 B, row0 = 8*phb-3, col0 = -3
    __shared__ float w1s[4 * 3 * 49];      // 2352 B
    __shared__ float ctile[4 * 5 * 52];    // 4160 B (4 oc x 5 conv rows x 51, pad 52)
    int blk = blockIdx.x;
    int b = blk / 48, rem48 = blk % 48;
    int ocq = rem48 / 6, phb = rem48 % 6;
    int oc0 = ocq * 4;
    int tid = threadIdx.x;
    int row0 = 8 * phb - 3;

    // stage weights (4 oc x 147)
    for (int i = tid; i < 588; i += 256) w1s[i] = w1[oc0 * 147 + i];
    // stage input tile, zero-padded
    for (int i = tid; i < 3 * 15 * 107; i += 256) {
        int ic = i / 1605, rem = i % 1605;
        int r = rem / 107, c = rem % 107;
        int gr = row0 + r, gc = c - 3;
        float v = 0.f;
        if (gr >= 0 && gr < Hh && gc >= 0 && gc < Ww)
            v = grid[((b * 3 + ic) * Hh + gr) * Ww + gc];
        tile[i] = v;
    }
    __syncthreads();

    // conv: 1020 tasks = 4 oc x 5 conv rows x 51 cols; 4 per thread
    for (int t = tid; t < 1020; t += 256) {
        int oc_l = t / 255, rem = t % 255;
        int r_l = rem / 51, ow = rem % 51;
        float acc = 0.f;
        for (int ic = 0; ic < 3; ++ic) {
            const float* wp = w1s + (oc_l * 3 + ic) * 49;
            const float* tp = tile + ic * 1605 + (2 * r_l) * 107 + 2 * ow;   // FIXED: 2*ow
            #pragma unroll
            for (int kh = 0; kh < 7; ++kh) {
                const float* lr = tp + kh * 107;
                #pragma unroll
                for (int kw = 0; kw < 7; ++kw)
                    acc += lr[kw] * wp[kh * 7 + kw];
            }
        }
        float bia = b1[oc0 + oc_l];
        ctile[(oc_l * 5 + r_l) * 52 + ow] = fmaxf(acc + bia, 0.f);
    }
    __syncthreads();

    // pool: 4 oc x 2 ph x 25 pw = 200 outputs
    if (tid < 200) {
        int oc_l = tid / 50, rem = tid % 50;
        int ph_l = rem / 25, pw = rem % 25;
        const float* cp = ctile + (oc_l * 5 + 2 * ph_l) * 52 + 2 * pw;
        float m = -INFINITY;
        #pragma unroll
        for (int r = 0; r < 3; ++r)
            #pragma unroll
            for (int c = 0; c < 3; ++c)
                m = fmaxf(m, cp[r * 52 + c]);
        int ph = 2 * phb + ph_l;
        p1[((b * 32 + oc0 + oc_l) * 12 + ph) * 25 + pw] = m;
    }
}

// ====== K2: conv2 + pool2 (R12 verbatim, known-good) ======
__global__ void conv2p2_kernel(const float* __restrict__ p1, const float* __restrict__ w2,
                               const float* __restrict__ b2, float* __restrict__ p2) {
    __shared__ float lds[32 * 16 * 29];
    int blk = blockIdx.x;
    int b = blk / 18;
    int tid = threadIdx.x;
    int u = (blk % 18) * 256 + tid;
    for (int i = tid; i < 32 * 16 * 29; i += 256) {
        int ic = i / 464, rem = i % 464;
        int r = rem / 29, c = rem % 29;
        int gr = r - 2, gc = c - 2;
        float v = 0.f;
        if (gr >= 0 && gr < 12 && gc >= 0 && gc < 25)
            v = p1[((b * 32 + ic) * 12 + gr) * 25 + gc];
        lds[i] = v;
    }
    __syncthreads();
    int pw = u % 12, ph = (u / 12) % 6, oc = u / 72;
    float acc[2][2] = {{0.f, 0.f}, {0.f, 0.f}};
    const float* wbase = w2 + oc * 32 * 25;
    const float* lbase = lds + (2 * ph) * 29 + 2 * pw;
    float wrA[25], wrB[25];
    #pragma unroll
    for (int k = 0; k < 25; ++k) wrA[k] = wbase[k];          // ic=0
    #define C2_BODY(IC, WCUR, WNXT, PREFETCH)                                   \
    {                                                                           \
        if (PREFETCH) {                                                         \
            const float* wpn = wbase + ((IC) + 1) * 25;                         \
            _Pragma("unroll")                                                   \
            for (int k = 0; k < 25; ++k) WNXT[k] = wpn[k];                      \
        }                                                                       \
        float inr[6][6];                                                        \
        const float* lp = lbase + (IC) * 464;                                   \
        _Pragma("unroll")                                                       \
        for (int r = 0; r < 6; ++r)                                             \
            _Pragma("unroll")                                                   \
            for (int c = 0; c < 6; ++c)                                         \
                inr[r][c] = lp[r * 29 + c];                                     \
        _Pragma("unroll")                                                       \
        for (int kh = 0; kh < 5; ++kh)                                          \
            _Pragma("unroll")                                                   \
            for (int kw = 0; kw < 5; ++kw)                                      \
                _Pragma("unroll")                                               \
                for (int dy = 0; dy < 2; ++dy)                                  \
                    _Pragma("unroll")                                           \
                    for (int dx = 0; dx < 2; ++dx)                              \
                        acc[dy][dx] += inr[dy + kh][dx + kw] * WCUR[kh * 5 + kw]; \
    }
    for (int ic = 0; ic < 32; ic += 2) {
        C2_BODY(ic,     wrA, wrB, true);
        C2_BODY(ic + 1, wrB, wrA, (ic + 2 < 32));
    }
    #undef C2_BODY
    float bia = b2[oc];
    float m = fmaxf(fmaxf(fmaxf(acc[0][0], acc[0][1]), fmaxf(acc[1][0], acc[1][1])) + bia, 0.f);
    p2[((b * 64 + oc) * 6 + ph) * 12 + pw] = m;
}

// ==== K3: conv3 + pool3 + feat publish + last-block head (R12 verbatim) ====
__global__ __launch_bounds__(256) void conv3p3_head_kernel(
        const float* __restrict__ p2, const float* __restrict__ w3,
        const float* __restrict__ b3, float* __restrict__ featbuf,
        unsigned* __restrict__ cnt,
        const float* __restrict__ wl1, const float* __restrict__ bl1,
        const float* __restrict__ wl2, const float* __restrict__ bl2,
        float* __restrict__ out) {
    __shared__ float smf[64 * 8 * 14];   // staged p2; later reused for feat/h2
    __shared__ float red[144];
    __shared__ unsigned lastflag;
    int blk = blockIdx.x;
    int b = blk / 16, blk16 = blk % 16;
    int tid = threadIdx.x;
    for (int i = tid; i < 64 * 8 * 14; i += 256) {
        int ic = i / 112, rem = i % 112;
        int r = rem / 14, c = rem % 14;
        int gr = r - 1, gc = c - 1;
        float v = 0.f;
        if (gr >= 0 && gr < 6 && gc >= 0 && gc < 12)
            v = p2[((b * 64 + ic) * 6 + gr) * 12 + gc];
        smf[i] = v;
    }
    __syncthreads();
    if (tid < 144) {
        int u = blk16 * 144 + tid;               // < 2304 = 128*18
        int pw = u % 6, ph = (u / 6) % 3, oc = u / 18;
        float acc[2][2] = {{0.f, 0.f}, {0.f, 0.f}};
        const float* wbase = w3 + oc * 64 * 9;
        const float* lbase = smf + (2 * ph) * 14 + 2 * pw;
        float wrA[9], wrB[9];
        #pragma unroll
        for (int k = 0; k < 9; ++k) wrA[k] = wbase[k];       // ic=0
        #define C3_BODY(IC, WCUR, WNXT, PREFETCH)                               \
        {                                                                       \
            if (PREFETCH) {                                                     \
                const float* wpn = wbase + ((IC) + 1) * 9;                      \
                _Pragma("unroll")                                               \
                for (int k = 0; k < 9; ++k) WNXT[k] = wpn[k];                   \
            }                                                                   \
            float inr[4][4];                                                    \
            const float* lp = lbase + (IC) * 112;                               \
            _Pragma("unroll")                                                   \
            for (int r = 0; r < 4; ++r)                                         \
                _Pragma("unroll")                                               \
                for (int c = 0; c < 4; ++c)                                     \
                    inr[r][c] = lp[r * 14 + c];                                 \
            _Pragma("unroll")                                                   \
            for (int kh = 0; kh < 3; ++kh)                                      \
                _Pragma("unroll")                                               \
                for (int kw = 0; kw < 3; ++kw)                                  \
                    _Pragma("unroll")                                           \
                    for (int dy = 0; dy < 2; ++dy)                              \
                        _Pragma("unroll")                                       \
                        for (int dx = 0; dx < 2; ++dx)                          \
                            acc[dy][dx] += inr[dy + kh][dx + kw] * WCUR[kh * 3 + kw]; \
        }
        for (int ic = 0; ic < 64; ic += 2) {
            C3_BODY(ic,     wrA, wrB, true);
            C3_BODY(ic + 1, wrB, wrA, (ic + 2 < 64));
        }
        #undef C3_BODY
        float bia = b3[oc];
        red[tid] = fmaxf(fmaxf(fmaxf(acc[0][0], acc[0][1]),
                               fmaxf(acc[1][0], acc[1][1])) + bia, 0.f);
    }
    __syncthreads();
    if (tid < 8) {   // reduce this block's 8 complete channels -> feat
        float s = 0.0f;
        #pragma unroll
        for (int k = 0; k < 18; ++k) s += red[tid * 18 + k];   // row-major spatial order
        __hip_atomic_store(&featbuf[b * 128 + blk16 * 8 + tid], s * (1.0f / 18.0f),
                           __ATOMIC_RELEASE, __HIP_MEMORY_SCOPE_AGENT);
    }
    // ---- arrival: 16th block of this b runs the head (no spinning) ----
    __syncthreads();
    if (tid == 0) {
        unsigned prev = __hip_atomic_fetch_add(&cnt[b], 1u, __ATOMIC_ACQ_REL,
                                               __HIP_MEMORY_SCOPE_AGENT);
        lastflag = (prev == 15u) ? 1u : 0u;
    }
    __syncthreads();
    if (lastflag) {
        float* feat = smf;        // overlay (p2 stage dead)
        float* h2 = smf + 128;
        int c = tid;
        if (c < 128)
            feat[c] = __hip_atomic_load(&featbuf[b * 128 + c],
                                        __ATOMIC_ACQUIRE, __HIP_MEMORY_SCOPE_AGENT);
        __syncthreads();
        if (c < 128) {
            float a = bl1[c];
            const float4* wr = (const float4*)(wl1 + c * 128);
            #pragma unroll 8
            for (int k4 = 0; k4 < 32; ++k4) {
                float4 w = wr[k4];
                a += feat[4 * k4] * w.x + feat[4 * k4 + 1] * w.y
                   + feat[4 * k4 + 2] * w.z + feat[4 * k4 + 3] * w.w;
            }
            h2[c] = fmaxf(a, 0.0f);
        }
        __syncthreads();
        if (c < 5) {
            float a2 = bl2[c];
            const float4* wr2 = (const float4*)(wl2 + c * 128);
            #pragma unroll 8
            for (int k4 = 0; k4 < 32; ++k4) {
                float4 w = wr2[k4];
                a2 += h2[4 * k4] * w.x + h2[4 * k4 + 1] * w.y
                    + h2[4 * k4 + 2] * w.z + h2[4 * k4 + 3] * w.w;
            }
            out[b * 5 + c] = a2;
        }
    }
}

// ---------------- launch ----------------
extern "C" void kernel_launch(void* const* d_in, const int* in_sizes, int n_in,
                              void* d_out, int out_size, void* d_ws, size_t ws_size,
                              hipStream_t stream) {
    const int*   x   = (const int*)d_in[0];
    const float* w1  = (const float*)d_in[1];
    const float* b1  = (const float*)d_in[2];
    const float* w2  = (const float*)d_in[3];
    const float* b2  = (const float*)d_in[4];
    const float* w3  = (const float*)d_in[5];
    const float* b3  = (const float*)d_in[6];
    const float* wl1 = (const float*)d_in[7];
    const float* bl1 = (const float*)d_in[8];
    const float* wl2 = (const float*)d_in[9];
    const float* bl2 = (const float*)d_in[10];
    float* out = (float*)d_out;

    // workspace:
    //   grid    @ 0       : 606000 B
    //   p1      @ 606000  : 384000 B
    //   p2g     @ 990000  : 184320 B
    //   featbuf @ 1174320 : 5120 B
    //   cnt     @ 1179440 : 40 B   (zeroed by K0 each launch, coherent stores)
    char* ws = (char*)d_ws;
    float*    grid    = (float*)ws;
    float*    p1      = (float*)(ws + 606000);
    float*    p2g     = (float*)(ws + 990000);
    float*    featbuf = (float*)(ws + 1174320);
    unsigned* cnt     = (unsigned*)(ws + 1179440);

    scatter_grid_kernel<<<30, 1024, 0, stream>>>(x, grid, cnt);
    conv1p1_kernel<<<480, 256, 0, stream>>>(grid, w1, b1, p1);
    conv2p2_kernel<<<180, 256, 0, stream>>>(p1, w2, b2, p2g);
    conv3p3_head_kernel<<<160, 256, 0, stream>>>(p2g, w3, b3, featbuf, cnt,
                                                 wl1, bl1, wl2, bl2, out);
}

// Round 15
// 82.576 us; speedup vs baseline: 1.1148x; 1.1148x over previous
//
#include <hip/hip_runtime.h>

// ---------------- problem constants ----------------
#define Bb 10
#define Hh 50
#define Ww 101
#define Kk 4096
#define SLICE (Hh*Ww)   // 5050

// conv1: IC=3 OC=32 k7 s2 p3 -> [32,25,51]; pool1 k3 s2 -> [32,12,25]
// conv2: IC=32 OC=64 k5 s1 p2 -> [64,12,25]; pool2 k2 s2 -> [64,6,12]
// conv3: IC=64 OC=128 k3 s1 p1 -> [128,6,12]; pool3 k2 s2 -> [128,3,6]
// head: mean(18) -> fc128 relu -> fc5

// ============ K0: scatter + separable 3x3 max-dilate + decode -> grid ============
__global__ __launch_bounds__(1024) void scatter_grid_kernel(
        const int* __restrict__ x, float* __restrict__ grid, unsigned* __restrict__ cnt) {
    __shared__ int lastKp[52 * 104];   // [row+1][col+1], border -1
    __shared__ int rowm[52 * 104];     // horizontal 3-max
    int bc = blockIdx.x;
    int tid = threadIdx.x;
    if (bc < Bb && tid == 0)
        __hip_atomic_store(&cnt[bc], 0u, __ATOMIC_RELEASE, __HIP_MEMORY_SCOPE_AGENT);
    for (int i = tid; i < 52 * 104; i += 1024) lastKp[i] = -1;
    __syncthreads();
    const int2* xp = (const int2*)(x + bc * Kk * 2);   // (col,row) pairs
    for (int k = tid; k < Kk + 1; k += 1024) {
        int col, row;
        if (k == 0) { col = 50; row = 48; }            // prepended base fill
        else { int2 p = xp[k - 1]; col = p.x; row = p.y; }
        atomicMax(&lastKp[(row + 1) * 104 + (col + 1)], k);
    }
    __syncthreads();
    for (int i = tid; i < 52 * 101; i += 1024) {       // row-max pass
        int r = i / 101, c = i % 101 + 1;
        const int* lp = &lastKp[r * 104 + c];
        rowm[r * 104 + c] = max(max(lp[-1], lp[0]), lp[1]);
    }
    __syncthreads();
    float* g = grid + bc * SLICE;                      // col-max + decode
    for (int i = tid; i < SLICE; i += 1024) {
        int r = i / Ww + 1, c = i % Ww + 1;
        int M = max(max(rowm[(r - 1) * 104 + c], rowm[r * 104 + c]),
                    rowm[(r + 1) * 104 + c]);
        g[i] = (M < 0) ? 0.0f : ((lastKp[r * 104 + c] == M) ? 1.0f : 0.5f);
    }
}

// ======== K1: conv1 + pool1 band-tiled (R14 verbatim, known-good) ========
__global__ __launch_bounds__(256) void conv1p1_kernel(
        const float* __restrict__ grid, const float* __restrict__ w1,
        const float* __restrict__ b1, float* __restrict__ p1) {
    __shared__ float tile[3 * 15 * 107];
    __shared__ float w1s[4 * 3 * 49];
    __shared__ float ctile[4 * 5 * 52];
    int blk = blockIdx.x;
    int b = blk / 48, rem48 = blk % 48;
    int ocq = rem48 / 6, phb = rem48 % 6;
    int oc0 = ocq * 4;
    int tid = threadIdx.x;
    int row0 = 8 * phb - 3;

    for (int i = tid; i < 588; i += 256) w1s[i] = w1[oc0 * 147 + i];
    for (int i = tid; i < 3 * 15 * 107; i += 256) {
        int ic = i / 1605, rem = i % 1605;
        int r = rem / 107, c = rem % 107;
        int gr = row0 + r, gc = c - 3;
        float v = 0.f;
        if (gr >= 0 && gr < Hh && gc >= 0 && gc < Ww)
            v = grid[((b * 3 + ic) * Hh + gr) * Ww + gc];
        tile[i] = v;
    }
    __syncthreads();
    for (int t = tid; t < 1020; t += 256) {
        int oc_l = t / 255, rem = t % 255;
        int r_l = rem / 51, ow = rem % 51;
        float acc = 0.f;
        for (int ic = 0; ic < 3; ++ic) {
            const float* wp = w1s + (oc_l * 3 + ic) * 49;
            const float* tp = tile + ic * 1605 + (2 * r_l) * 107 + 2 * ow;
            #pragma unroll
            for (int kh = 0; kh < 7; ++kh) {
                const float* lr = tp + kh * 107;
                #pragma unroll
                for (int kw = 0; kw < 7; ++kw)
                    acc += lr[kw] * wp[kh * 7 + kw];
            }
        }
        float bia = b1[oc0 + oc_l];
        ctile[(oc_l * 5 + r_l) * 52 + ow] = fmaxf(acc + bia, 0.f);
    }
    __syncthreads();
    if (tid < 200) {
        int oc_l = tid / 50, rem = tid % 50;
        int ph_l = rem / 25, pw = rem % 25;
        const float* cp = ctile + (oc_l * 5 + 2 * ph_l) * 52 + 2 * pw;
        float m = -INFINITY;
        #pragma unroll
        for (int r = 0; r < 3; ++r)
            #pragma unroll
            for (int c = 0; c < 3; ++c)
                m = fmaxf(m, cp[r * 52 + c]);
        int ph = 2 * phb + ph_l;
        p1[((b * 32 + oc0 + oc_l) * 12 + ph) * 25 + pw] = m;
    }
}

// ====== K2 v2: conv2 + pool2, 512 threads, ic-split halves (TLP + half chains) ======
// 180 blocks x 512. Threads [0,256) and [256,512) compute the SAME 256 outputs
// over ic [0,16) and [16,32); partials meet in LDS; half 0 finalizes.
__global__ __launch_bounds__(512) void conv2p2_kernel(
        const float* __restrict__ p1, const float* __restrict__ w2,
        const float* __restrict__ b2, float* __restrict__ p2) {
    __shared__ float lds[32 * 16 * 29];   // 59392 B
    __shared__ float part[256 * 4];       // 4096 B  (total 63488 < 65536)
    int blk = blockIdx.x;
    int b = blk / 18;
    int tid = threadIdx.x;
    for (int i = tid; i < 32 * 16 * 29; i += 512) {
        int ic = i / 464, rem = i % 464;
        int r = rem / 29, c = rem % 29;
        int gr = r - 2, gc = c - 2;
        float v = 0.f;
        if (gr >= 0 && gr < 12 && gc >= 0 && gc < 25)
            v = p1[((b * 32 + ic) * 12 + gr) * 25 + gc];
        lds[i] = v;
    }
    __syncthreads();
    int u_l = tid & 255, half = tid >> 8;
    int u = (blk % 18) * 256 + u_l;
    int pw = u % 12, ph = (u / 12) % 6, oc = u / 72;
    float acc[2][2] = {{0.f, 0.f}, {0.f, 0.f}};
    const float* wbase = w2 + oc * 32 * 25;
    const float* lbase = lds + (2 * ph) * 29 + 2 * pw;
    int ic0 = half * 16;
    for (int ic = ic0; ic < ic0 + 16; ++ic) {
        float inr[6][6];
        const float* lp = lbase + ic * 464;
        #pragma unroll
        for (int r = 0; r < 6; ++r)
            #pragma unroll
            for (int c = 0; c < 6; ++c)
                inr[r][c] = lp[r * 29 + c];
        const float* wp = wbase + ic * 25;
        float wr[25];
        #pragma unroll
        for (int k = 0; k < 25; ++k) wr[k] = wp[k];
        #pragma unroll
        for (int kh = 0; kh < 5; ++kh)
            #pragma unroll
            for (int kw = 0; kw < 5; ++kw)
                #pragma unroll
                for (int dy = 0; dy < 2; ++dy)
                    #pragma unroll
                    for (int dx = 0; dx < 2; ++dx)
                        acc[dy][dx] += inr[dy + kh][dx + kw] * wr[kh * 5 + kw];
    }
    if (half == 1) {
        #pragma unroll
        for (int dy = 0; dy < 2; ++dy)
            #pragma unroll
            for (int dx = 0; dx < 2; ++dx)
                part[u_l * 4 + dy * 2 + dx] = acc[dy][dx];
    }
    __syncthreads();
    if (half == 0) {
        #pragma unroll
        for (int dy = 0; dy < 2; ++dy)
            #pragma unroll
            for (int dx = 0; dx < 2; ++dx)
                acc[dy][dx] += part[u_l * 4 + dy * 2 + dx];
        float bia = b2[oc];
        float m = fmaxf(fmaxf(fmaxf(acc[0][0], acc[0][1]),
                              fmaxf(acc[1][0], acc[1][1])) + bia, 0.f);
        p2[((b * 64 + oc) * 6 + ph) * 12 + pw] = m;
    }
}

// ==== K3 v2: conv3+pool3+head, 512 threads, ic-split halves ====
// 160 blocks (16/b). lid<144 of each half computes the block's 144 outputs over
// ic [0,32)/[32,64); partial reduce in LDS; half 0 finalizes -> red; feat publish
// + arrival + head identical to R12 (proven).
__global__ __launch_bounds__(512) void conv3p3_head_kernel(
        const float* __restrict__ p2, const float* __restrict__ w3,
        const float* __restrict__ b3, float* __restrict__ featbuf,
        unsigned* __restrict__ cnt,
        const float* __restrict__ wl1, const float* __restrict__ bl1,
        const float* __restrict__ wl2, const float* __restrict__ bl2,
        float* __restrict__ out) {
    __shared__ float smf[64 * 8 * 14];   // staged p2; later reused for feat/h2
    __shared__ float part[144 * 4];
    __shared__ float red[144];
    __shared__ unsigned lastflag;
    int blk = blockIdx.x;
    int b = blk / 16, blk16 = blk % 16;
    int tid = threadIdx.x;
    for (int i = tid; i < 64 * 8 * 14; i += 512) {
        int ic = i / 112, rem = i % 112;
        int r = rem / 14, c = rem % 14;
        int gr = r - 1, gc = c - 1;
        float v = 0.f;
        if (gr >= 0 && gr < 6 && gc >= 0 && gc < 12)
            v = p2[((b * 64 + ic) * 6 + gr) * 12 + gc];
        smf[i] = v;
    }
    __syncthreads();
    int lid = tid & 255, half = tid >> 8;
    float acc[2][2] = {{0.f, 0.f}, {0.f, 0.f}};
    int u = blk16 * 144 + lid;               // < 2304 = 128*18 when lid<144
    int pw = u % 6, ph = (u / 6) % 3, oc = u / 18;
    if (lid < 144) {
        const float* wbase = w3 + oc * 64 * 9;
        const float* lbase = smf + (2 * ph) * 14 + 2 * pw;
        int ic0 = half * 32;
        for (int ic = ic0; ic < ic0 + 32; ++ic) {
            float inr[4][4];
            const float* lp = lbase + ic * 112;
            #pragma unroll
            for (int r = 0; r < 4; ++r)
                #pragma unroll
                for (int c = 0; c < 4; ++c)
                    inr[r][c] = lp[r * 14 + c];
            const float* wp = wbase + ic * 9;
            float wr[9];
            #pragma unroll
            for (int k = 0; k < 9; ++k) wr[k] = wp[k];
            #pragma unroll
            for (int kh = 0; kh < 3; ++kh)
                #pragma unroll
                for (int kw = 0; kw < 3; ++kw)
                    #pragma unroll
                    for (int dy = 0; dy < 2; ++dy)
                        #pragma unroll
                        for (int dx = 0; dx < 2; ++dx)
                            acc[dy][dx] += inr[dy + kh][dx + kw] * wr[kh * 3 + kw];
        }
        if (half == 1) {
            #pragma unroll
            for (int dy = 0; dy < 2; ++dy)
                #pragma unroll
                for (int dx = 0; dx < 2; ++dx)
                    part[lid * 4 + dy * 2 + dx] = acc[dy][dx];
        }
    }
    __syncthreads();
    if (half == 0 && lid < 144) {
        #pragma unroll
        for (int dy = 0; dy < 2; ++dy)
            #pragma unroll
            for (int dx = 0; dx < 2; ++dx)
                acc[dy][dx] += part[lid * 4 + dy * 2 + dx];
        float bia = b3[oc];
        red[lid] = fmaxf(fmaxf(fmaxf(acc[0][0], acc[0][1]),
                               fmaxf(acc[1][0], acc[1][1])) + bia, 0.f);
    }
    __syncthreads();
    if (tid < 8) {   // reduce this block's 8 complete channels -> feat
        float s = 0.0f;
        #pragma unroll
        for (int k = 0; k < 18; ++k) s += red[tid * 18 + k];   // row-major spatial order
        __hip_atomic_store(&featbuf[b * 128 + blk16 * 8 + tid], s * (1.0f / 18.0f),
                           __ATOMIC_RELEASE, __HIP_MEMORY_SCOPE_AGENT);
    }
    // ---- arrival: 16th block of this b runs the head (no spinning) ----
    __syncthreads();
    if (tid == 0) {
        unsigned prev = __hip_atomic_fetch_add(&cnt[b], 1u, __ATOMIC_ACQ_REL,
                                               __HIP_MEMORY_SCOPE_AGENT);
        lastflag = (prev == 15u) ? 1u : 0u;
    }
    __syncthreads();
    if (lastflag) {
        float* feat = smf;        // overlay (p2 stage dead)
        float* h2 = smf + 128;
        int c = tid;
        if (c < 128)
            feat[c] = __hip_atomic_load(&featbuf[b * 128 + c],
                                        __ATOMIC_ACQUIRE, __HIP_MEMORY_SCOPE_AGENT);
        __syncthreads();
        if (c < 128) {
            float a = bl1[c];
            const float4* wr = (const float4*)(wl1 + c * 128);
            #pragma unroll 8
            for (int k4 = 0; k4 < 32; ++k4) {
                float4 w = wr[k4];
                a += feat[4 * k4] * w.x + feat[4 * k4 + 1] * w.y
                   + feat[4 * k4 + 2] * w.z + feat[4 * k4 + 3] * w.w;
            }
            h2[c] = fmaxf(a, 0.0f);
        }
        __syncthreads();
        if (c < 5) {
            float a2 = bl2[c];
            const float4* wr2 = (const float4*)(wl2 + c * 128);
            #pragma unroll 8
            for (int k4 = 0; k4 < 32; ++k4) {
                float4 w = wr2[k4];
                a2 += h2[4 * k4] * w.x + h2[4 * k4 + 1] * w.y
                    + h2[4 * k4 + 2] * w.z + h2[4 * k4 + 3] * w.w;
            }
            out[b * 5 + c] = a2;
        }
    }
}

// ---------------- launch ----------------
extern "C" void kernel_launch(void* const* d_in, const int* in_sizes, int n_in,
                              void* d_out, int out_size, void* d_ws, size_t ws_size,
                              hipStream_t stream) {
    const int*   x   = (const int*)d_in[0];
    const float* w1  = (const float*)d_in[1];
    const float* b1  = (const float*)d_in[2];
    const float* w2  = (const float*)d_in[3];
    const float* b2  = (const float*)d_in[4];
    const float* w3  = (const float*)d_in[5];
    const float* b3  = (const float*)d_in[6];
    const float* wl1 = (const float*)d_in[7];
    const float* bl1 = (const float*)d_in[8];
    const float* wl2 = (const float*)d_in[9];
    const float* bl2 = (const float*)d_in[10];
    float* out = (float*)d_out;

    // workspace:
    //   grid    @ 0       : 606000 B
    //   p1      @ 606000  : 384000 B
    //   p2g     @ 990000  : 184320 B
    //   featbuf @ 1174320 : 5120 B
    //   cnt     @ 1179440 : 40 B   (zeroed by K0 each launch, coherent stores)
    char* ws = (char*)d_ws;
    float*    grid    = (float*)ws;
    float*    p1      = (float*)(ws + 606000);
    float*    p2g     = (float*)(ws + 990000);
    float*    featbuf = (float*)(ws + 1174320);
    unsigned* cnt     = (unsigned*)(ws + 1179440);

    scatter_grid_kernel<<<30, 1024, 0, stream>>>(x, grid, cnt);
    conv1p1_kernel<<<480, 256, 0, stream>>>(grid, w1, b1, p1);
    conv2p2_kernel<<<180, 512, 0, stream>>>(p1, w2, b2, p2g);
    conv3p3_head_kernel<<<160, 512, 0, stream>>>(p2g, w3, b3, featbuf, cnt,
                                                 wl1, bl1, wl2, bl2, out);
}

// Round 16
// 72.775 us; speedup vs baseline: 1.2649x; 1.1347x over previous
//
#include <hip/hip_runtime.h>

// ---------------- problem constants ----------------
#define Bb 10
#define Hh 50
#define Ww 101
#define Kk 4096
#define SLICE (Hh*Ww)   // 5050

// conv1: IC=3 OC=32 k7 s2 p3 -> [32,25,51]; pool1 k3 s2 -> [32,12,25]
// conv2: IC=32 OC=64 k5 s1 p2 -> [64,12,25]; pool2 k2 s2 -> [64,6,12]
// conv3: IC=64 OC=128 k3 s1 p1 -> [128,6,12]; pool3 k2 s2 -> [128,3,6]
// head: mean(18) -> fc128 relu -> fc5

// ============ K0: scatter + separable 3x3 max-dilate + decode -> grid ============
__global__ __launch_bounds__(1024) void scatter_grid_kernel(
        const int* __restrict__ x, float* __restrict__ grid, unsigned* __restrict__ cnt) {
    __shared__ int lastKp[52 * 104];   // [row+1][col+1], border -1
    __shared__ int rowm[52 * 104];     // horizontal 3-max
    int bc = blockIdx.x;
    int tid = threadIdx.x;
    if (bc < Bb && tid == 0)
        __hip_atomic_store(&cnt[bc], 0u, __ATOMIC_RELEASE, __HIP_MEMORY_SCOPE_AGENT);
    for (int i = tid; i < 52 * 104; i += 1024) lastKp[i] = -1;
    __syncthreads();
    const int2* xp = (const int2*)(x + bc * Kk * 2);   // (col,row) pairs
    for (int k = tid; k < Kk + 1; k += 1024) {
        int col, row;
        if (k == 0) { col = 50; row = 48; }            // prepended base fill
        else { int2 p = xp[k - 1]; col = p.x; row = p.y; }
        atomicMax(&lastKp[(row + 1) * 104 + (col + 1)], k);
    }
    __syncthreads();
    for (int i = tid; i < 52 * 101; i += 1024) {       // row-max pass
        int r = i / 101, c = i % 101 + 1;
        const int* lp = &lastKp[r * 104 + c];
        rowm[r * 104 + c] = max(max(lp[-1], lp[0]), lp[1]);
    }
    __syncthreads();
    float* g = grid + bc * SLICE;                      // col-max + decode
    for (int i = tid; i < SLICE; i += 1024) {
        int r = i / Ww + 1, c = i % Ww + 1;
        int M = max(max(rowm[(r - 1) * 104 + c], rowm[r * 104 + c]),
                    rowm[(r + 1) * 104 + c]);
        g[i] = (M < 0) ? 0.0f : ((lastKp[r * 104 + c] == M) ? 1.0f : 0.5f);
    }
}

// ======== K1 v4: conv1 + pool1 band-tiled, quad tasks (ILP 4) ========
// 480 blocks (b, ocq8, phb6) x 256 threads. Task = (oc_l 4, r_l 5, quad 13):
// 260 tasks, acc[4] adjacent cols sharing the s[13] window (R8 ILP pattern).
// Tile [3][15][109] so the 13-wide window stays in-bounds at quad=12.
__global__ __launch_bounds__(256) void conv1p1_kernel(
        const float* __restrict__ grid, const float* __restrict__ w1,
        const float* __restrict__ b1, float* __restrict__ p1) {
    __shared__ float tile[3 * 15 * 109];   // 19620 B; row0 = 8*phb-3, col0 = -3
    __shared__ float w1s[4 * 3 * 49];      // 2352 B
    __shared__ float ctile[4 * 5 * 52];    // 4160 B
    int blk = blockIdx.x;
    int b = blk / 48, rem48 = blk % 48;
    int ocq = rem48 / 6, phb = rem48 % 6;
    int oc0 = ocq * 4;
    int tid = threadIdx.x;
    int row0 = 8 * phb - 3;

    for (int i = tid; i < 588; i += 256) w1s[i] = w1[oc0 * 147 + i];
    for (int i = tid; i < 3 * 15 * 109; i += 256) {
        int ic = i / 1635, rem = i % 1635;
        int r = rem / 109, c = rem % 109;
        int gr = row0 + r, gc = c - 3;
        float v = 0.f;
        if (gr >= 0 && gr < Hh && gc >= 0 && gc < Ww)
            v = grid[((b * 3 + ic) * Hh + gr) * Ww + gc];
        tile[i] = v;
    }
    __syncthreads();
    // 260 tasks = 4 oc_l x 5 r_l x 13 quads; acc[4] per task
    for (int t = tid; t < 260; t += 256) {
        int oc_l = t / 65, rem = t % 65;
        int r_l = rem / 13, quad = rem % 13;
        int ow0 = quad * 4;
        float acc[4] = {0.f, 0.f, 0.f, 0.f};
        for (int ic = 0; ic < 3; ++ic) {
            const float* wp = w1s + (oc_l * 3 + ic) * 49;
            const float* tp = tile + ic * 1635 + (2 * r_l) * 109 + 8 * quad;
            #pragma unroll
            for (int kh = 0; kh < 7; ++kh) {
                const float* lr = tp + kh * 109;
                float s[13];
                #pragma unroll
                for (int k = 0; k < 13; ++k) s[k] = lr[k];
                float wa[7];
                #pragma unroll
                for (int k = 0; k < 7; ++k) wa[k] = wp[kh * 7 + k];
                #pragma unroll
                for (int kw = 0; kw < 7; ++kw)
                    #pragma unroll
                    for (int j = 0; j < 4; ++j)
                        acc[j] += s[2 * j + kw] * wa[kw];
            }
        }
        float bia = b1[oc0 + oc_l];
        #pragma unroll
        for (int j = 0; j < 4; ++j) {
            int ow = ow0 + j;
            if (ow < 51)
                ctile[(oc_l * 5 + r_l) * 52 + ow] = fmaxf(acc[j] + bia, 0.f);
        }
    }
    __syncthreads();
    if (tid < 200) {   // pool: 4 oc x 2 ph x 25 pw
        int oc_l = tid / 50, rem = tid % 50;
        int ph_l = rem / 25, pw = rem % 25;
        const float* cp = ctile + (oc_l * 5 + 2 * ph_l) * 52 + 2 * pw;
        float m = -INFINITY;
        #pragma unroll
        for (int r = 0; r < 3; ++r)
            #pragma unroll
            for (int c = 0; c < 3; ++c)
                m = fmaxf(m, cp[r * 52 + c]);
        int ph = 2 * phb + ph_l;
        p1[((b * 32 + oc0 + oc_l) * 12 + ph) * 25 + pw] = m;
    }
}

// ====== K2 v3: conv2 + pool2, 1024 threads, 4-way ic-split (chain 8) ======
// 180 blocks x 1024. Quarter q handles ics [8q, 8q+8) of the SAME 256 outputs;
// serial part-buffer reduce: q0 += q1, += q2, += q3 (one 4KB buffer, 3 rounds).
__global__ __launch_bounds__(1024) void conv2p2_kernel(
        const float* __restrict__ p1, const float* __restrict__ w2,
        const float* __restrict__ b2, float* __restrict__ p2) {
    __shared__ float lds[32 * 16 * 29];   // 59392 B
    __shared__ float part[256 * 4];       // 4096 B  (total 63488 < 65536)
    int blk = blockIdx.x;
    int b = blk / 18;
    int tid = threadIdx.x;
    for (int i = tid; i < 32 * 16 * 29; i += 1024) {
        int ic = i / 464, rem = i % 464;
        int r = rem / 29, c = rem % 29;
        int gr = r - 2, gc = c - 2;
        float v = 0.f;
        if (gr >= 0 && gr < 12 && gc >= 0 && gc < 25)
            v = p1[((b * 32 + ic) * 12 + gr) * 25 + gc];
        lds[i] = v;
    }
    __syncthreads();
    int u_l = tid & 255, q = tid >> 8;
    int u = (blk % 18) * 256 + u_l;
    int pw = u % 12, ph = (u / 12) % 6, oc = u / 72;
    float acc[2][2] = {{0.f, 0.f}, {0.f, 0.f}};
    const float* wbase = w2 + oc * 32 * 25;
    const float* lbase = lds + (2 * ph) * 29 + 2 * pw;
    int ic0 = q * 8;
    for (int ic = ic0; ic < ic0 + 8; ++ic) {
        float inr[6][6];
        const float* lp = lbase + ic * 464;
        #pragma unroll
        for (int r = 0; r < 6; ++r)
            #pragma unroll
            for (int c = 0; c < 6; ++c)
                inr[r][c] = lp[r * 29 + c];
        const float* wp = wbase + ic * 25;
        float wr[25];
        #pragma unroll
        for (int k = 0; k < 25; ++k) wr[k] = wp[k];
        #pragma unroll
        for (int kh = 0; kh < 5; ++kh)
            #pragma unroll
            for (int kw = 0; kw < 5; ++kw)
                #pragma unroll
                for (int dy = 0; dy < 2; ++dy)
                    #pragma unroll
                    for (int dx = 0; dx < 2; ++dx)
                        acc[dy][dx] += inr[dy + kh][dx + kw] * wr[kh * 5 + kw];
    }
    // serial reduce q1, q2, q3 into q0 (order ((q0+q1)+q2)+q3)
    #pragma unroll
    for (int src = 1; src < 4; ++src) {
        if (q == src) {
            #pragma unroll
            for (int dy = 0; dy < 2; ++dy)
                #pragma unroll
                for (int dx = 0; dx < 2; ++dx)
                    part[u_l * 4 + dy * 2 + dx] = acc[dy][dx];
        }
        __syncthreads();
        if (q == 0) {
            #pragma unroll
            for (int dy = 0; dy < 2; ++dy)
                #pragma unroll
                for (int dx = 0; dx < 2; ++dx)
                    acc[dy][dx] += part[u_l * 4 + dy * 2 + dx];
        }
        if (src < 3) __syncthreads();
    }
    if (q == 0) {
        float bia = b2[oc];
        float m = fmaxf(fmaxf(fmaxf(acc[0][0], acc[0][1]),
                              fmaxf(acc[1][0], acc[1][1])) + bia, 0.f);
        p2[((b * 64 + oc) * 6 + ph) * 12 + pw] = m;
    }
}

// ==== K3 v3: conv3+pool3+head, 1024 threads, 4-way ic-split (chain 16) ====
__global__ __launch_bounds__(1024) void conv3p3_head_kernel(
        const float* __restrict__ p2, const float* __restrict__ w3,
        const float* __restrict__ b3, float* __restrict__ featbuf,
        unsigned* __restrict__ cnt,
        const float* __restrict__ wl1, const float* __restrict__ bl1,
        const float* __restrict__ wl2, const float* __restrict__ bl2,
        float* __restrict__ out) {
    __shared__ float smf[64 * 8 * 14];   // staged p2; later reused for feat/h2
    __shared__ float part[144 * 4];
    __shared__ float red[144];
    __shared__ unsigned lastflag;
    int blk = blockIdx.x;
    int b = blk / 16, blk16 = blk % 16;
    int tid = threadIdx.x;
    for (int i = tid; i < 64 * 8 * 14; i += 1024) {
        int ic = i / 112, rem = i % 112;
        int r = rem / 14, c = rem % 14;
        int gr = r - 1, gc = c - 1;
        float v = 0.f;
        if (gr >= 0 && gr < 6 && gc >= 0 && gc < 12)
            v = p2[((b * 64 + ic) * 6 + gr) * 12 + gc];
        smf[i] = v;
    }
    __syncthreads();
    int lid = tid & 255, q = tid >> 8;
    float acc[2][2] = {{0.f, 0.f}, {0.f, 0.f}};
    int u = blk16 * 144 + lid;               // < 2304 = 128*18 when lid<144
    int pw = u % 6, ph = (u / 6) % 3, oc = u / 18;
    if (lid < 144) {
        const float* wbase = w3 + oc * 64 * 9;
        const float* lbase = smf + (2 * ph) * 14 + 2 * pw;
        int ic0 = q * 16;
        for (int ic = ic0; ic < ic0 + 16; ++ic) {
            float inr[4][4];
            const float* lp = lbase + ic * 112;
            #pragma unroll
            for (int r = 0; r < 4; ++r)
                #pragma unroll
                for (int c = 0; c < 4; ++c)
                    inr[r][c] = lp[r * 14 + c];
            const float* wp = wbase + ic * 9;
            float wr[9];
            #pragma unroll
            for (int k = 0; k < 9; ++k) wr[k] = wp[k];
            #pragma unroll
            for (int kh = 0; kh < 3; ++kh)
                #pragma unroll
                for (int kw = 0; kw < 3; ++kw)
                    #pragma unroll
                    for (int dy = 0; dy < 2; ++dy)
                        #pragma unroll
                        for (int dx = 0; dx < 2; ++dx)
                            acc[dy][dx] += inr[dy + kh][dx + kw] * wr[kh * 3 + kw];
        }
    }
    // serial reduce q1, q2, q3 into q0
    #pragma unroll
    for (int src = 1; src < 4; ++src) {
        if (q == src && lid < 144) {
            #pragma unroll
            for (int dy = 0; dy < 2; ++dy)
                #pragma unroll
                for (int dx = 0; dx < 2; ++dx)
                    part[lid * 4 + dy * 2 + dx] = acc[dy][dx];
        }
        __syncthreads();
        if (q == 0 && lid < 144) {
            #pragma unroll
            for (int dy = 0; dy < 2; ++dy)
                #pragma unroll
                for (int dx = 0; dx < 2; ++dx)
                    acc[dy][dx] += part[lid * 4 + dy * 2 + dx];
        }
        if (src < 3) __syncthreads();
    }
    if (q == 0 && lid < 144) {
        float bia = b3[oc];
        red[lid] = fmaxf(fmaxf(fmaxf(acc[0][0], acc[0][1]),
                               fmaxf(acc[1][0], acc[1][1])) + bia, 0.f);
    }
    __syncthreads();
    if (tid < 8) {   // reduce this block's 8 complete channels -> feat
        float s = 0.0f;
        #pragma unroll
        for (int k = 0; k < 18; ++k) s += red[tid * 18 + k];   // row-major spatial order
        __hip_atomic_store(&featbuf[b * 128 + blk16 * 8 + tid], s * (1.0f / 18.0f),
                           __ATOMIC_RELEASE, __HIP_MEMORY_SCOPE_AGENT);
    }
    // ---- arrival: 16th block of this b runs the head (no spinning) ----
    __syncthreads();
    if (tid == 0) {
        unsigned prev = __hip_atomic_fetch_add(&cnt[b], 1u, __ATOMIC_ACQ_REL,
                                               __HIP_MEMORY_SCOPE_AGENT);
        lastflag = (prev == 15u) ? 1u : 0u;
    }
    __syncthreads();
    if (lastflag) {
        float* feat = smf;        // overlay (p2 stage dead)
        float* h2 = smf + 128;
        int c = tid;
        if (c < 128)
            feat[c] = __hip_atomic_load(&featbuf[b * 128 + c],
                                        __ATOMIC_ACQUIRE, __HIP_MEMORY_SCOPE_AGENT);
        __syncthreads();
        if (c < 128) {
            float a = bl1[c];
            const float4* wr = (const float4*)(wl1 + c * 128);
            #pragma unroll 8
            for (int k4 = 0; k4 < 32; ++k4) {
                float4 w = wr[k4];
                a += feat[4 * k4] * w.x + feat[4 * k4 + 1] * w.y
                   + feat[4 * k4 + 2] * w.z + feat[4 * k4 + 3] * w.w;
            }
            h2[c] = fmaxf(a, 0.0f);
        }
        __syncthreads();
        if (c < 5) {
            float a2 = bl2[c];
            const float4* wr2 = (const float4*)(wl2 + c * 128);
            #pragma unroll 8
            for (int k4 = 0; k4 < 32; ++k4) {
                float4 w = wr2[k4];
                a2 += h2[4 * k4] * w.x + h2[4 * k4 + 1] * w.y
                    + h2[4 * k4 + 2] * w.z + h2[4 * k4 + 3] * w.w;
            }
            out[b * 5 + c] = a2;
        }
    }
}

// ---------------- launch ----------------
extern "C" void kernel_launch(void* const* d_in, const int* in_sizes, int n_in,
                              void* d_out, int out_size, void* d_ws, size_t ws_size,
                              hipStream_t stream) {
    const int*   x   = (const int*)d_in[0];
    const float* w1  = (const float*)d_in[1];
    const float* b1  = (const float*)d_in[2];
    const float* w2  = (const float*)d_in[3];
    const float* b2  = (const float*)d_in[4];
    const float* w3  = (const float*)d_in[5];
    const float* b3  = (const float*)d_in[6];
    const float* wl1 = (const float*)d_in[7];
    const float* bl1 = (const float*)d_in[8];
    const float* wl2 = (const float*)d_in[9];
    const float* bl2 = (const float*)d_in[10];
    float* out = (float*)d_out;

    // workspace:
    //   grid    @ 0       : 606000 B
    //   p1      @ 606000  : 384000 B
    //   p2g     @ 990000  : 184320 B
    //   featbuf @ 1174320 : 5120 B
    //   cnt     @ 1179440 : 40 B   (zeroed by K0 each launch, coherent stores)
    char* ws = (char*)d_ws;
    float*    grid    = (float*)ws;
    float*    p1      = (float*)(ws + 606000);
    float*    p2g     = (float*)(ws + 990000);
    float*    featbuf = (float*)(ws + 1174320);
    unsigned* cnt     = (unsigned*)(ws + 1179440);

    scatter_grid_kernel<<<30, 1024, 0, stream>>>(x, grid, cnt);
    conv1p1_kernel<<<480, 256, 0, stream>>>(grid, w1, b1, p1);
    conv2p2_kernel<<<180, 1024, 0, stream>>>(p1, w2, b2, p2g);
    conv3p3_head_kernel<<<160, 1024, 0, stream>>>(p2g, w3, b3, featbuf, cnt,
                                                  wl1, bl1, wl2, bl2, out);
}

// Round 17
// 64.156 us; speedup vs baseline: 1.4348x; 1.1343x over previous
//
#include <hip/hip_runtime.h>

// ---------------- problem constants ----------------
#define Bb 10
#define Hh 50
#define Ww 101
#define Kk 4096
#define SLICE (Hh*Ww)   // 5050

// conv1: IC=3 OC=32 k7 s2 p3 -> [32,25,51]; pool1 k3 s2 -> [32,12,25]
// conv2: IC=32 OC=64 k5 s1 p2 -> [64,12,25]; pool2 k2 s2 -> [64,6,12]
// conv3: IC=64 OC=128 k3 s1 p1 -> [128,6,12]; pool3 k2 s2 -> [128,3,6]
// head: mean(18) -> fc128 relu -> fc5

// ============ K0: scatter + separable 3x3 max-dilate + decode -> grid ============
__global__ __launch_bounds__(1024) void scatter_grid_kernel(
        const int* __restrict__ x, float* __restrict__ grid, unsigned* __restrict__ cnt) {
    __shared__ int lastKp[52 * 104];   // [row+1][col+1], border -1
    __shared__ int rowm[52 * 104];     // horizontal 3-max
    int bc = blockIdx.x;
    int tid = threadIdx.x;
    if (bc < Bb && tid == 0)
        __hip_atomic_store(&cnt[bc], 0u, __ATOMIC_RELEASE, __HIP_MEMORY_SCOPE_AGENT);
    for (int i = tid; i < 52 * 104; i += 1024) lastKp[i] = -1;
    __syncthreads();
    const int2* xp = (const int2*)(x + bc * Kk * 2);   // (col,row) pairs
    for (int k = tid; k < Kk + 1; k += 1024) {
        int col, row;
        if (k == 0) { col = 50; row = 48; }            // prepended base fill
        else { int2 p = xp[k - 1]; col = p.x; row = p.y; }
        atomicMax(&lastKp[(row + 1) * 104 + (col + 1)], k);
    }
    __syncthreads();
    for (int i = tid; i < 52 * 101; i += 1024) {       // row-max pass
        int r = i / 101, c = i % 101 + 1;
        const int* lp = &lastKp[r * 104 + c];
        rowm[r * 104 + c] = max(max(lp[-1], lp[0]), lp[1]);
    }
    __syncthreads();
    float* g = grid + bc * SLICE;                      // col-max + decode
    for (int i = tid; i < SLICE; i += 1024) {
        int r = i / Ww + 1, c = i % Ww + 1;
        int M = max(max(rowm[(r - 1) * 104 + c], rowm[r * 104 + c]),
                    rowm[(r + 1) * 104 + c]);
        g[i] = (M < 0) ? 0.0f : ((lastKp[r * 104 + c] == M) ? 1.0f : 0.5f);
    }
}

// ======== K1 v5: conv1 + pool1 band-tiled, quad tasks, 512 threads ========
// 480 blocks (b, ocq8, phb6) x 512. 260 tasks -> every thread <= 1 task
// (R16's 256-thread version had a 2-deep imbalanced tail on 4 threads).
__global__ __launch_bounds__(512) void conv1p1_kernel(
        const float* __restrict__ grid, const float* __restrict__ w1,
        const float* __restrict__ b1, float* __restrict__ p1) {
    __shared__ float tile[3 * 15 * 109];   // 19620 B; row0 = 8*phb-3, col0 = -3
    __shared__ float w1s[4 * 3 * 49];      // 2352 B
    __shared__ float ctile[4 * 5 * 52];    // 4160 B
    int blk = blockIdx.x;
    int b = blk / 48, rem48 = blk % 48;
    int ocq = rem48 / 6, phb = rem48 % 6;
    int oc0 = ocq * 4;
    int tid = threadIdx.x;
    int row0 = 8 * phb - 3;

    for (int i = tid; i < 588; i += 512) w1s[i] = w1[oc0 * 147 + i];
    for (int i = tid; i < 3 * 15 * 109; i += 512) {
        int ic = i / 1635, rem = i % 1635;
        int r = rem / 109, c = rem % 109;
        int gr = row0 + r, gc = c - 3;
        float v = 0.f;
        if (gr >= 0 && gr < Hh && gc >= 0 && gc < Ww)
            v = grid[((b * 3 + ic) * Hh + gr) * Ww + gc];
        tile[i] = v;
    }
    __syncthreads();
    // 260 tasks = 4 oc_l x 5 r_l x 13 quads; acc[4] per task; <=1 task/thread
    if (tid < 260) {
        int t = tid;
        int oc_l = t / 65, rem = t % 65;
        int r_l = rem / 13, quad = rem % 13;
        int ow0 = quad * 4;
        float acc[4] = {0.f, 0.f, 0.f, 0.f};
        for (int ic = 0; ic < 3; ++ic) {
            const float* wp = w1s + (oc_l * 3 + ic) * 49;
            const float* tp = tile + ic * 1635 + (2 * r_l) * 109 + 8 * quad;
            #pragma unroll
            for (int kh = 0; kh < 7; ++kh) {
                const float* lr = tp + kh * 109;
                float s[13];
                #pragma unroll
                for (int k = 0; k < 13; ++k) s[k] = lr[k];
                float wa[7];
                #pragma unroll
                for (int k = 0; k < 7; ++k) wa[k] = wp[kh * 7 + k];
                #pragma unroll
                for (int kw = 0; kw < 7; ++kw)
                    #pragma unroll
                    for (int j = 0; j < 4; ++j)
                        acc[j] += s[2 * j + kw] * wa[kw];
            }
        }
        float bia = b1[oc0 + oc_l];
        #pragma unroll
        for (int j = 0; j < 4; ++j) {
            int ow = ow0 + j;
            if (ow < 51)
                ctile[(oc_l * 5 + r_l) * 52 + ow] = fmaxf(acc[j] + bia, 0.f);
        }
    }
    __syncthreads();
    if (tid < 200) {   // pool: 4 oc x 2 ph x 25 pw
        int oc_l = tid / 50, rem = tid % 50;
        int ph_l = rem / 25, pw = rem % 25;
        const float* cp = ctile + (oc_l * 5 + 2 * ph_l) * 52 + 2 * pw;
        float m = -INFINITY;
        #pragma unroll
        for (int r = 0; r < 3; ++r)
            #pragma unroll
            for (int c = 0; c < 3; ++c)
                m = fmaxf(m, cp[r * 52 + c]);
        int ph = 2 * phb + ph_l;
        p1[((b * 32 + oc0 + oc_l) * 12 + ph) * 25 + pw] = m;
    }
}

// ====== K2 v4: conv2 + pool2, ph-halved tiles, 8-way ic-split (chain 4) ======
// 360 blocks = b(10) x sh(2) x blkl(18), 1024 threads. Quarter q = tid>>7
// (128 lanes, ALL active) handles ics [4q,4q+4) of the same 128 outputs.
// Staged window: padded rows [6sh, 6sh+10) -> [32][10][29] = 37120 B.
// Single-sync ordered reduce: q0 += q1 ... += q7.
__global__ __launch_bounds__(1024) void conv2p2_kernel(
        const float* __restrict__ p1, const float* __restrict__ w2,
        const float* __restrict__ b2, float* __restrict__ p2) {
    __shared__ float lds2[32 * 10 * 29];   // 37120 B
    __shared__ float part[7 * 128 * 4];    // 14336 B (total 51456 < 65536)
    int blk = blockIdx.x;
    int b = blk / 36, rem36 = blk % 36;
    int sh = rem36 / 18, blkl = rem36 % 18;
    int tid = threadIdx.x;
    for (int i = tid; i < 32 * 10 * 29; i += 1024) {
        int ic = i / 290, rem = i % 290;
        int pr_l = rem / 29, c = rem % 29;
        int gr = 6 * sh + pr_l - 2, gc = c - 2;
        float v = 0.f;
        if (gr >= 0 && gr < 12 && gc >= 0 && gc < 25)
            v = p1[((b * 32 + ic) * 12 + gr) * 25 + gc];
        lds2[i] = v;
    }
    __syncthreads();
    int lid = tid & 127, q = tid >> 7;
    int u = blkl * 128 + lid;                 // [0,2304) within this (b,sh) half
    int pw = u % 12, ph_l = (u / 12) % 3, oc = u / 36;
    float acc[2][2] = {{0.f, 0.f}, {0.f, 0.f}};
    const float* wbase = w2 + oc * 32 * 25;
    const float* lbase = lds2 + (2 * ph_l) * 29 + 2 * pw;
    int ic0 = q * 4;
    for (int ic = ic0; ic < ic0 + 4; ++ic) {
        float inr[6][6];
        const float* lp = lbase + ic * 290;
        #pragma unroll
        for (int r = 0; r < 6; ++r)
            #pragma unroll
            for (int c = 0; c < 6; ++c)
                inr[r][c] = lp[r * 29 + c];
        const float* wp = wbase + ic * 25;
        float wr[25];
        #pragma unroll
        for (int k = 0; k < 25; ++k) wr[k] = wp[k];
        #pragma unroll
        for (int kh = 0; kh < 5; ++kh)
            #pragma unroll
            for (int kw = 0; kw < 5; ++kw)
                #pragma unroll
                for (int dy = 0; dy < 2; ++dy)
                    #pragma unroll
                    for (int dx = 0; dx < 2; ++dx)
                        acc[dy][dx] += inr[dy + kh][dx + kw] * wr[kh * 5 + kw];
    }
    if (q > 0) {
        #pragma unroll
        for (int dy = 0; dy < 2; ++dy)
            #pragma unroll
            for (int dx = 0; dx < 2; ++dx)
                part[((q - 1) * 128 + lid) * 4 + dy * 2 + dx] = acc[dy][dx];
    }
    __syncthreads();
    if (q == 0) {
        #pragma unroll
        for (int src = 0; src < 7; ++src)     // fixed order q1..q7
            #pragma unroll
            for (int dy = 0; dy < 2; ++dy)
                #pragma unroll
                for (int dx = 0; dx < 2; ++dx)
                    acc[dy][dx] += part[(src * 128 + lid) * 4 + dy * 2 + dx];
        float bia = b2[oc];
        float m = fmaxf(fmaxf(fmaxf(acc[0][0], acc[0][1]),
                              fmaxf(acc[1][0], acc[1][1])) + bia, 0.f);
        int ph = 3 * sh + ph_l;
        p2[((b * 64 + oc) * 6 + ph) * 12 + pw] = m;
    }
}

// ==== K3 v4: conv3+pool3+head, 7-way ic-split (chain 9/10, 1008 active) ====
// 160 blocks (16/b) x 1024. q = tid/144 (q<7 active, 144 lanes each); q<6
// handles ics [9q,9q+9), q==6 handles [54,64). Single-sync ordered reduce.
// Block owns 8 complete channels -> feat publish / arrival / head unchanged.
__global__ __launch_bounds__(1024) void conv3p3_head_kernel(
        const float* __restrict__ p2, const float* __restrict__ w3,
        const float* __restrict__ b3, float* __restrict__ featbuf,
        unsigned* __restrict__ cnt,
        const float* __restrict__ wl1, const float* __restrict__ bl1,
        const float* __restrict__ wl2, const float* __restrict__ bl2,
        float* __restrict__ out) {
    __shared__ float smf[64 * 8 * 14];   // 28672 B; staged p2, later feat/h2
    __shared__ float part[6 * 144 * 4];  // 13824 B
    __shared__ float red[144];
    __shared__ unsigned lastflag;
    int blk = blockIdx.x;
    int b = blk / 16, blk16 = blk % 16;
    int tid = threadIdx.x;
    for (int i = tid; i < 64 * 8 * 14; i += 1024) {
        int ic = i / 112, rem = i % 112;
        int r = rem / 14, c = rem % 14;
        int gr = r - 1, gc = c - 1;
        float v = 0.f;
        if (gr >= 0 && gr < 6 && gc >= 0 && gc < 12)
            v = p2[((b * 64 + ic) * 6 + gr) * 12 + gc];
        smf[i] = v;
    }
    __syncthreads();
    int q = tid / 144, lid = tid % 144;
    bool act = q < 7;
    float acc[2][2] = {{0.f, 0.f}, {0.f, 0.f}};
    int u = blk16 * 144 + lid;               // < 2304 = 128*18
    int pw = u % 6, ph = (u / 6) % 3, oc = u / 18;
    if (act) {
        const float* wbase = w3 + oc * 64 * 9;
        const float* lbase = smf + (2 * ph) * 14 + 2 * pw;
        int ic0 = q * 9;
        int ic1 = (q == 6) ? 64 : ic0 + 9;
        for (int ic = ic0; ic < ic1; ++ic) {
            float inr[4][4];
            const float* lp = lbase + ic * 112;
            #pragma unroll
            for (int r = 0; r < 4; ++r)
                #pragma unroll
                for (int c = 0; c < 4; ++c)
                    inr[r][c] = lp[r * 14 + c];
            const float* wp = wbase + ic * 9;
            float wr[9];
            #pragma unroll
            for (int k = 0; k < 9; ++k) wr[k] = wp[k];
            #pragma unroll
            for (int kh = 0; kh < 3; ++kh)
                #pragma unroll
                for (int kw = 0; kw < 3; ++kw)
                    #pragma unroll
                    for (int dy = 0; dy < 2; ++dy)
                        #pragma unroll
                        for (int dx = 0; dx < 2; ++dx)
                            acc[dy][dx] += inr[dy + kh][dx + kw] * wr[kh * 3 + kw];
        }
        if (q > 0) {
            #pragma unroll
            for (int dy = 0; dy < 2; ++dy)
                #pragma unroll
                for (int dx = 0; dx < 2; ++dx)
                    part[((q - 1) * 144 + lid) * 4 + dy * 2 + dx] = acc[dy][dx];
        }
    }
    __syncthreads();
    if (q == 0) {
        #pragma unroll
        for (int src = 0; src < 6; ++src)    // fixed order q1..q6
            #pragma unroll
            for (int dy = 0; dy < 2; ++dy)
                #pragma unroll
                for (int dx = 0; dx < 2; ++dx)
                    acc[dy][dx] += part[(src * 144 + lid) * 4 + dy * 2 + dx];
        float bia = b3[oc];
        red[lid] = fmaxf(fmaxf(fmaxf(acc[0][0], acc[0][1]),
                               fmaxf(acc[1][0], acc[1][1])) + bia, 0.f);
    }
    __syncthreads();
    if (tid < 8) {   // reduce this block's 8 complete channels -> feat
        float s = 0.0f;
        #pragma unroll
        for (int k = 0; k < 18; ++k) s += red[tid * 18 + k];   // row-major spatial order
        __hip_atomic_store(&featbuf[b * 128 + blk16 * 8 + tid], s * (1.0f / 18.0f),
                           __ATOMIC_RELEASE, __HIP_MEMORY_SCOPE_AGENT);
    }
    // ---- arrival: 16th block of this b runs the head (no spinning) ----
    __syncthreads();
    if (tid == 0) {
        unsigned prev = __hip_atomic_fetch_add(&cnt[b], 1u, __ATOMIC_ACQ_REL,
                                               __HIP_MEMORY_SCOPE_AGENT);
        lastflag = (prev == 15u) ? 1u : 0u;
    }
    __syncthreads();
    if (lastflag) {
        float* feat = smf;        // overlay (p2 stage dead)
        float* h2 = smf + 128;
        int c = tid;
        if (c < 128)
            feat[c] = __hip_atomic_load(&featbuf[b * 128 + c],
                                        __ATOMIC_ACQUIRE, __HIP_MEMORY_SCOPE_AGENT);
        __syncthreads();
        if (c < 128) {
            float a = bl1[c];
            const float4* wr = (const float4*)(wl1 + c * 128);
            #pragma unroll 8
            for (int k4 = 0; k4 < 32; ++k4) {
                float4 w = wr[k4];
                a += feat[4 * k4] * w.x + feat[4 * k4 + 1] * w.y
                   + feat[4 * k4 + 2] * w.z + feat[4 * k4 + 3] * w.w;
            }
            h2[c] = fmaxf(a, 0.0f);
        }
        __syncthreads();
        if (c < 5) {
            float a2 = bl2[c];
            const float4* wr2 = (const float4*)(wl2 + c * 128);
            #pragma unroll 8
            for (int k4 = 0; k4 < 32; ++k4) {
                float4 w = wr2[k4];
                a2 += h2[4 * k4] * w.x + h2[4 * k4 + 1] * w.y
                    + h2[4 * k4 + 2] * w.z + h2[4 * k4 + 3] * w.w;
            }
            out[b * 5 + c] = a2;
        }
    }
}

// ---------------- launch ----------------
extern "C" void kernel_launch(void* const* d_in, const int* in_sizes, int n_in,
                              void* d_out, int out_size, void* d_ws, size_t ws_size,
                              hipStream_t stream) {
    const int*   x   = (const int*)d_in[0];
    const float* w1  = (const float*)d_in[1];
    const float* b1  = (const float*)d_in[2];
    const float* w2  = (const float*)d_in[3];
    const float* b2  = (const float*)d_in[4];
    const float* w3  = (const float*)d_in[5];
    const float* b3  = (const float*)d_in[6];
    const float* wl1 = (const float*)d_in[7];
    const float* bl1 = (const float*)d_in[8];
    const float* wl2 = (const float*)d_in[9];
    const float* bl2 = (const float*)d_in[10];
    float* out = (float*)d_out;

    // workspace:
    //   grid    @ 0       : 606000 B
    //   p1      @ 606000  : 384000 B
    //   p2g     @ 990000  : 184320 B
    //   featbuf @ 1174320 : 5120 B
    //   cnt     @ 1179440 : 40 B   (zeroed by K0 each launch, coherent stores)
    char* ws = (char*)d_ws;
    float*    grid    = (float*)ws;
    float*    p1      = (float*)(ws + 606000);
    float*    p2g     = (float*)(ws + 990000);
    float*    featbuf = (float*)(ws + 1174320);
    unsigned* cnt     = (unsigned*)(ws + 1179440);

    scatter_grid_kernel<<<30, 1024, 0, stream>>>(x, grid, cnt);
    conv1p1_kernel<<<480, 512, 0, stream>>>(grid, w1, b1, p1);
    conv2p2_kernel<<<360, 1024, 0, stream>>>(p1, w2, b2, p2g);
    conv3p3_head_kernel<<<160, 1024, 0, stream>>>(p2g, w3, b3, featbuf, cnt,
                                                  wl1, bl1, wl2, bl2, out);
}

// Round 18
// 62.377 us; speedup vs baseline: 1.4758x; 1.0285x over previous
//
#include <hip/hip_runtime.h>

// ---------------- problem constants ----------------
#define Bb 10
#define Hh 50
#define Ww 101
#define Kk 4096
#define SLICE (Hh*Ww)   // 5050

// conv1: IC=3 OC=32 k7 s2 p3 -> [32,25,51]; pool1 k3 s2 -> [32,12,25]
// conv2: IC=32 OC=64 k5 s1 p2 -> [64,12,25]; pool2 k2 s2 -> [64,6,12]
// conv3: IC=64 OC=128 k3 s1 p1 -> [128,6,12]; pool3 k2 s2 -> [128,3,6]
// head: mean(18) -> fc128 relu -> fc5

// ============ K0: scatter + separable 3x3 max-dilate + decode -> grid ============
__global__ __launch_bounds__(1024) void scatter_grid_kernel(
        const int* __restrict__ x, float* __restrict__ grid, unsigned* __restrict__ cnt) {
    __shared__ int lastKp[52 * 104];   // [row+1][col+1], border -1
    __shared__ int rowm[52 * 104];     // horizontal 3-max
    int bc = blockIdx.x;
    int tid = threadIdx.x;
    if (bc < Bb && tid == 0)
        __hip_atomic_store(&cnt[bc], 0u, __ATOMIC_RELEASE, __HIP_MEMORY_SCOPE_AGENT);
    for (int i = tid; i < 52 * 104; i += 1024) lastKp[i] = -1;
    __syncthreads();
    const int2* xp = (const int2*)(x + bc * Kk * 2);   // (col,row) pairs
    for (int k = tid; k < Kk + 1; k += 1024) {
        int col, row;
        if (k == 0) { col = 50; row = 48; }            // prepended base fill
        else { int2 p = xp[k - 1]; col = p.x; row = p.y; }
        atomicMax(&lastKp[(row + 1) * 104 + (col + 1)], k);
    }
    __syncthreads();
    for (int i = tid; i < 52 * 101; i += 1024) {       // row-max pass
        int r = i / 101, c = i % 101 + 1;
        const int* lp = &lastKp[r * 104 + c];
        rowm[r * 104 + c] = max(max(lp[-1], lp[0]), lp[1]);
    }
    __syncthreads();
    float* g = grid + bc * SLICE;                      // col-max + decode
    for (int i = tid; i < SLICE; i += 1024) {
        int r = i / Ww + 1, c = i % Ww + 1;
        int M = max(max(rowm[(r - 1) * 104 + c], rowm[r * 104 + c]),
                    rowm[(r + 1) * 104 + c]);
        g[i] = (M < 0) ? 0.0f : ((lastKp[r * 104 + c] == M) ? 1.0f : 0.5f);
    }
}

// ======== K1 v6: conv1 + pool1 band-tiled, 1024 threads, 3-way ic-split ========
// 480 blocks (b, ocq8, phb6) x 1024. 780 tasks = ic(3) x (oc_l 4, r_l 5, quad 13);
// each task: acc[4] over ONE ic (chain/acc 49, was 147). ic>0 partials via LDS;
// ic==0 threads reduce in fixed order (ic0+ic1+ic2) and write ctile.
__global__ __launch_bounds__(1024) void conv1p1_kernel(
        const float* __restrict__ grid, const float* __restrict__ w1,
        const float* __restrict__ b1, float* __restrict__ p1) {
    __shared__ float tile[3 * 15 * 109];   // 19620 B; row0 = 8*phb-3, col0 = -3
    __shared__ float w1s[4 * 3 * 49];      // 2352 B
    __shared__ float ctile[4 * 5 * 52];    // 4160 B
    __shared__ float part[2 * 260 * 4];    // 8320 B  (total 34452)
    int blk = blockIdx.x;
    int b = blk / 48, rem48 = blk % 48;
    int ocq = rem48 / 6, phb = rem48 % 6;
    int oc0 = ocq * 4;
    int tid = threadIdx.x;
    int row0 = 8 * phb - 3;

    for (int i = tid; i < 588; i += 1024) w1s[i] = w1[oc0 * 147 + i];
    for (int i = tid; i < 3 * 15 * 109; i += 1024) {
        int ic = i / 1635, rem = i % 1635;
        int r = rem / 109, c = rem % 109;
        int gr = row0 + r, gc = c - 3;
        float v = 0.f;
        if (gr >= 0 && gr < Hh && gc >= 0 && gc < Ww)
            v = grid[((b * 3 + ic) * Hh + gr) * Ww + gc];
        tile[i] = v;
    }
    __syncthreads();
    int s = tid % 260, ic = tid / 260;     // task split
    bool act = tid < 780;
    int oc_l = s / 65, srem = s % 65;
    int r_l = srem / 13, quad = srem % 13;
    float acc[4] = {0.f, 0.f, 0.f, 0.f};
    if (act) {
        const float* wp = w1s + (oc_l * 3 + ic) * 49;
        const float* tp = tile + ic * 1635 + (2 * r_l) * 109 + 8 * quad;
        #pragma unroll
        for (int kh = 0; kh < 7; ++kh) {
            const float* lr = tp + kh * 109;
            float sw[13];
            #pragma unroll
            for (int k = 0; k < 13; ++k) sw[k] = lr[k];
            float wa[7];
            #pragma unroll
            for (int k = 0; k < 7; ++k) wa[k] = wp[kh * 7 + k];
            #pragma unroll
            for (int kw = 0; kw < 7; ++kw)
                #pragma unroll
                for (int j = 0; j < 4; ++j)
                    acc[j] += sw[2 * j + kw] * wa[kw];
        }
        if (ic > 0) {
            #pragma unroll
            for (int j = 0; j < 4; ++j)
                part[((ic - 1) * 260 + s) * 4 + j] = acc[j];
        }
    }
    __syncthreads();
    if (tid < 260) {   // ic==0 threads: reduce ic1, ic2 (fixed order), finalize
        #pragma unroll
        for (int src = 0; src < 2; ++src)
            #pragma unroll
            for (int j = 0; j < 4; ++j)
                acc[j] += part[(src * 260 + s) * 4 + j];
        float bia = b1[oc0 + oc_l];
        int ow0 = quad * 4;
        #pragma unroll
        for (int j = 0; j < 4; ++j) {
            int ow = ow0 + j;
            if (ow < 51)
                ctile[(oc_l * 5 + r_l) * 52 + ow] = fmaxf(acc[j] + bia, 0.f);
        }
    }
    __syncthreads();
    if (tid < 200) {   // pool: 4 oc x 2 ph x 25 pw
        int oc_l2 = tid / 50, rem = tid % 50;
        int ph_l = rem / 25, pw = rem % 25;
        const float* cp = ctile + (oc_l2 * 5 + 2 * ph_l) * 52 + 2 * pw;
        float m = -INFINITY;
        #pragma unroll
        for (int r = 0; r < 3; ++r)
            #pragma unroll
            for (int c = 0; c < 3; ++c)
                m = fmaxf(m, cp[r * 52 + c]);
        int ph = 2 * phb + ph_l;
        p1[((b * 32 + oc0 + oc_l2) * 12 + ph) * 25 + pw] = m;
    }
}

// ====== K2 v5: conv2 + pool2, ph-halved tiles, 64-lane groups, 16-way ic-split ======
// 720 blocks = b(10) x sh(2) x blkl(36), 1024 threads. Group q = tid>>6 (16 groups
// x 64 lanes, all active) handles ics [2q, 2q+2) of the same 64 outputs (chain 2).
// Staged window rows [6sh-2, 6sh+8) -> [32][10][29] = 37120 B; part 15*64*4 floats.
__global__ __launch_bounds__(1024) void conv2p2_kernel(
        const float* __restrict__ p1, const float* __restrict__ w2,
        const float* __restrict__ b2, float* __restrict__ p2) {
    __shared__ float lds2[32 * 10 * 29];   // 37120 B
    __shared__ float part[15 * 64 * 4];    // 15360 B (total 52480 < 65536)
    int blk = blockIdx.x;
    int b = blk / 72, rem72 = blk % 72;
    int sh = rem72 / 36, blkl = rem72 % 36;
    int tid = threadIdx.x;
    for (int i = tid; i < 32 * 10 * 29; i += 1024) {
        int ic = i / 290, rem = i % 290;
        int pr_l = rem / 29, c = rem % 29;
        int gr = 6 * sh + pr_l - 2, gc = c - 2;
        float v = 0.f;
        if (gr >= 0 && gr < 12 && gc >= 0 && gc < 25)
            v = p1[((b * 32 + ic) * 12 + gr) * 25 + gc];
        lds2[i] = v;
    }
    __syncthreads();
    int lid = tid & 63, q = tid >> 6;
    int u = blkl * 64 + lid;                  // [0,2304) within this (b,sh) half
    int pw = u % 12, ph_l = (u / 12) % 3, oc = u / 36;
    float acc[2][2] = {{0.f, 0.f}, {0.f, 0.f}};
    const float* wbase = w2 + oc * 32 * 25;
    const float* lbase = lds2 + (2 * ph_l) * 29 + 2 * pw;
    int ic0 = q * 2;
    for (int ic = ic0; ic < ic0 + 2; ++ic) {
        float inr[6][6];
        const float* lp = lbase + ic * 290;
        #pragma unroll
        for (int r = 0; r < 6; ++r)
            #pragma unroll
            for (int c = 0; c < 6; ++c)
                inr[r][c] = lp[r * 29 + c];
        const float* wp = wbase + ic * 25;
        float wr[25];
        #pragma unroll
        for (int k = 0; k < 25; ++k) wr[k] = wp[k];
        #pragma unroll
        for (int kh = 0; kh < 5; ++kh)
            #pragma unroll
            for (int kw = 0; kw < 5; ++kw)
                #pragma unroll
                for (int dy = 0; dy < 2; ++dy)
                    #pragma unroll
                    for (int dx = 0; dx < 2; ++dx)
                        acc[dy][dx] += inr[dy + kh][dx + kw] * wr[kh * 5 + kw];
    }
    if (q > 0) {
        #pragma unroll
        for (int dy = 0; dy < 2; ++dy)
            #pragma unroll
            for (int dx = 0; dx < 2; ++dx)
                part[((q - 1) * 64 + lid) * 4 + dy * 2 + dx] = acc[dy][dx];
    }
    __syncthreads();
    if (q == 0) {
        #pragma unroll
        for (int src = 0; src < 15; ++src)    // fixed order q1..q15
            #pragma unroll
            for (int dy = 0; dy < 2; ++dy)
                #pragma unroll
                for (int dx = 0; dx < 2; ++dx)
                    acc[dy][dx] += part[(src * 64 + lid) * 4 + dy * 2 + dx];
        float bia = b2[oc];
        float m = fmaxf(fmaxf(fmaxf(acc[0][0], acc[0][1]),
                              fmaxf(acc[1][0], acc[1][1])) + bia, 0.f);
        int ph = 3 * sh + ph_l;
        p2[((b * 64 + oc) * 6 + ph) * 12 + pw] = m;
    }
}

// ==== K3 v4: conv3+pool3+head, 7-way ic-split (R17 verbatim, known-good) ====
__global__ __launch_bounds__(1024) void conv3p3_head_kernel(
        const float* __restrict__ p2, const float* __restrict__ w3,
        const float* __restrict__ b3, float* __restrict__ featbuf,
        unsigned* __restrict__ cnt,
        const float* __restrict__ wl1, const float* __restrict__ bl1,
        const float* __restrict__ wl2, const float* __restrict__ bl2,
        float* __restrict__ out) {
    __shared__ float smf[64 * 8 * 14];   // 28672 B; staged p2, later feat/h2
    __shared__ float part[6 * 144 * 4];  // 13824 B
    __shared__ float red[144];
    __shared__ unsigned lastflag;
    int blk = blockIdx.x;
    int b = blk / 16, blk16 = blk % 16;
    int tid = threadIdx.x;
    for (int i = tid; i < 64 * 8 * 14; i += 1024) {
        int ic = i / 112, rem = i % 112;
        int r = rem / 14, c = rem % 14;
        int gr = r - 1, gc = c - 1;
        float v = 0.f;
        if (gr >= 0 && gr < 6 && gc >= 0 && gc < 12)
            v = p2[((b * 64 + ic) * 6 + gr) * 12 + gc];
        smf[i] = v;
    }
    __syncthreads();
    int q = tid / 144, lid = tid % 144;
    bool act = q < 7;
    float acc[2][2] = {{0.f, 0.f}, {0.f, 0.f}};
    int u = blk16 * 144 + lid;               // < 2304 = 128*18
    int pw = u % 6, ph = (u / 6) % 3, oc = u / 18;
    if (act) {
        const float* wbase = w3 + oc * 64 * 9;
        const float* lbase = smf + (2 * ph) * 14 + 2 * pw;
        int ic0 = q * 9;
        int ic1 = (q == 6) ? 64 : ic0 + 9;
        for (int ic = ic0; ic < ic1; ++ic) {
            float inr[4][4];
            const float* lp = lbase + ic * 112;
            #pragma unroll
            for (int r = 0; r < 4; ++r)
                #pragma unroll
                for (int c = 0; c < 4; ++c)
                    inr[r][c] = lp[r * 14 + c];
            const float* wp = wbase + ic * 9;
            float wr[9];
            #pragma unroll
            for (int k = 0; k < 9; ++k) wr[k] = wp[k];
            #pragma unroll
            for (int kh = 0; kh < 3; ++kh)
                #pragma unroll
                for (int kw = 0; kw < 3; ++kw)
                    #pragma unroll
                    for (int dy = 0; dy < 2; ++dy)
                        #pragma unroll
                        for (int dx = 0; dx < 2; ++dx)
                            acc[dy][dx] += inr[dy + kh][dx + kw] * wr[kh * 3 + kw];
        }
        if (q > 0) {
            #pragma unroll
            for (int dy = 0; dy < 2; ++dy)
                #pragma unroll
                for (int dx = 0; dx < 2; ++dx)
                    part[((q - 1) * 144 + lid) * 4 + dy * 2 + dx] = acc[dy][dx];
        }
    }
    __syncthreads();
    if (q == 0) {
        #pragma unroll
        for (int src = 0; src < 6; ++src)    // fixed order q1..q6
            #pragma unroll
            for (int dy = 0; dy < 2; ++dy)
                #pragma unroll
                for (int dx = 0; dx < 2; ++dx)
                    acc[dy][dx] += part[(src * 144 + lid) * 4 + dy * 2 + dx];
        float bia = b3[oc];
        red[lid] = fmaxf(fmaxf(fmaxf(acc[0][0], acc[0][1]),
                               fmaxf(acc[1][0], acc[1][1])) + bia, 0.f);
    }
    __syncthreads();
    if (tid < 8) {   // reduce this block's 8 complete channels -> feat
        float s = 0.0f;
        #pragma unroll
        for (int k = 0; k < 18; ++k) s += red[tid * 18 + k];   // row-major spatial order
        __hip_atomic_store(&featbuf[b * 128 + blk16 * 8 + tid], s * (1.0f / 18.0f),
                           __ATOMIC_RELEASE, __HIP_MEMORY_SCOPE_AGENT);
    }
    // ---- arrival: 16th block of this b runs the head (no spinning) ----
    __syncthreads();
    if (tid == 0) {
        unsigned prev = __hip_atomic_fetch_add(&cnt[b], 1u, __ATOMIC_ACQ_REL,
                                               __HIP_MEMORY_SCOPE_AGENT);
        lastflag = (prev == 15u) ? 1u : 0u;
    }
    __syncthreads();
    if (lastflag) {
        float* feat = smf;        // overlay (p2 stage dead)
        float* h2 = smf + 128;
        int c = tid;
        if (c < 128)
            feat[c] = __hip_atomic_load(&featbuf[b * 128 + c],
                                        __ATOMIC_ACQUIRE, __HIP_MEMORY_SCOPE_AGENT);
        __syncthreads();
        if (c < 128) {
            float a = bl1[c];
            const float4* wr = (const float4*)(wl1 + c * 128);
            #pragma unroll 8
            for (int k4 = 0; k4 < 32; ++k4) {
                float4 w = wr[k4];
                a += feat[4 * k4] * w.x + feat[4 * k4 + 1] * w.y
                   + feat[4 * k4 + 2] * w.z + feat[4 * k4 + 3] * w.w;
            }
            h2[c] = fmaxf(a, 0.0f);
        }
        __syncthreads();
        if (c < 5) {
            float a2 = bl2[c];
            const float4* wr2 = (const float4*)(wl2 + c * 128);
            #pragma unroll 8
            for (int k4 = 0; k4 < 32; ++k4) {
                float4 w = wr2[k4];
                a2 += h2[4 * k4] * w.x + h2[4 * k4 + 1] * w.y
                    + h2[4 * k4 + 2] * w.z + h2[4 * k4 + 3] * w.w;
            }
            out[b * 5 + c] = a2;
        }
    }
}

// ---------------- launch ----------------
extern "C" void kernel_launch(void* const* d_in, const int* in_sizes, int n_in,
                              void* d_out, int out_size, void* d_ws, size_t ws_size,
                              hipStream_t stream) {
    const int*   x   = (const int*)d_in[0];
    const float* w1  = (const float*)d_in[1];
    const float* b1  = (const float*)d_in[2];
    const float* w2  = (const float*)d_in[3];
    const float* b2  = (const float*)d_in[4];
    const float* w3  = (const float*)d_in[5];
    const float* b3  = (const float*)d_in[6];
    const float* wl1 = (const float*)d_in[7];
    const float* bl1 = (const float*)d_in[8];
    const float* wl2 = (const float*)d_in[9];
    const float* bl2 = (const float*)d_in[10];
    float* out = (float*)d_out;

    // workspace:
    //   grid    @ 0       : 606000 B
    //   p1      @ 606000  : 384000 B
    //   p2g     @ 990000  : 184320 B
    //   featbuf @ 1174320 : 5120 B
    //   cnt     @ 1179440 : 40 B   (zeroed by K0 each launch, coherent stores)
    char* ws = (char*)d_ws;
    float*    grid    = (float*)ws;
    float*    p1      = (float*)(ws + 606000);
    float*    p2g     = (float*)(ws + 990000);
    float*    featbuf = (float*)(ws + 1174320);
    unsigned* cnt     = (unsigned*)(ws + 1179440);

    scatter_grid_kernel<<<30, 1024, 0, stream>>>(x, grid, cnt);
    conv1p1_kernel<<<480, 1024, 0, stream>>>(grid, w1, b1, p1);
    conv2p2_kernel<<<720, 1024, 0, stream>>>(p1, w2, b2, p2g);
    conv3p3_head_kernel<<<160, 1024, 0, stream>>>(p2g, w3, b3, featbuf, cnt,
                                                  wl1, bl1, wl2, bl2, out);
}